// Round 9
// baseline (108.605 us; speedup 1.0000x reference)
//
#include <hip/hip_runtime.h>
#include <hip/hip_bf16.h>

typedef __bf16 v8bf __attribute__((ext_vector_type(8)));
typedef float f32x4 __attribute__((ext_vector_type(4)));
typedef float f32x16 __attribute__((ext_vector_type(16)));
typedef int v2i __attribute__((ext_vector_type(2)));
typedef int v4i __attribute__((ext_vector_type(4)));

#define MFMA16(a, b, c) __builtin_amdgcn_mfma_f32_16x16x32_bf16(a, b, c, 0, 0, 0)
#define MFMA32(a, b, c) __builtin_amdgcn_mfma_f32_32x32x16_bf16(a, b, c, 0, 0, 0)
#define GLOAD16(gp, lp)                                                        \
  __builtin_amdgcn_global_load_lds(                                            \
      (const __attribute__((address_space(1))) void*)(gp),                     \
      (__attribute__((address_space(3))) void*)(lp), 16, 0, 0)

// q scale = SCALE * log2(e) so that exp2(qk) == exp(qk*SCALE)
#define QSCALE 0.18033688011112042f

// ---------------- K0: weights -> MFMA-fragment-ordered bf16 ----------------
// wfrag[nb(6)][kk(8)][n(4)][lane(64)][8]: lane(g=l>>4,c=l&15) holds
//   wT row nb*64+n*16+c, cols kk*32+8g..+7  (wT = W^T; q part pre-scaled)
// owfrag[nb(4)][kk(8)][n(4)][lane][8] likewise for out_w^T.
__global__ __launch_bounds__(256) void k_cvt_w(const float* __restrict__ qw,
                                               const float* __restrict__ kw,
                                               const float* __restrict__ vw,
                                               const float* __restrict__ ow,
                                               __bf16* __restrict__ wfrag,
                                               __bf16* __restrict__ owfrag) {
  int t = blockIdx.x * 256 + threadIdx.x;  // 640*256 = 163840
  if (t < 98304) {
    int e = t & 7, idx = t >> 3;
    int l = idx & 63; idx >>= 6;
    int n = idx & 3; idx >>= 2;
    int kk = idx & 7, nb = idx >> 3;
    int nn = nb * 64 + n * 16 + (l & 15);
    int k = kk * 32 + 8 * (l >> 4) + e;
    float v;
    if (nn < 256) v = qw[k * 256 + nn] * QSCALE;
    else if (nn < 320) v = kw[k * 64 + (nn - 256)];
    else v = vw[k * 64 + (nn - 320)];
    wfrag[t] = (__bf16)v;
  } else {
    int u = t - 98304;
    int e = u & 7, idx = u >> 3;
    int l = idx & 63; idx >>= 6;
    int n = idx & 3; idx >>= 2;
    int kk = idx & 7, nb = idx >> 3;
    int nn = nb * 64 + n * 16 + (l & 15);
    int k = kk * 32 + 8 * (l >> 4) + e;
    owfrag[u] = (__bf16)ow[k * 256 + nn];
  }
}

// ---------------- K1: fused QKV projection GEMM ----------------
// M=32768, N=384, K=256. grid 1024 = 512 mb x 2 nh (3 N-tiles each);
// A-frags in registers (x read direct fp32->bf16); B-loads are dense
// fragment-ordered 16B/lane (zero address divergence).
__global__ __launch_bounds__(256) void k_qkv(const float* __restrict__ x,
                                             const __bf16* __restrict__ wfrag,
                                             const float* __restrict__ qb,
                                             const float* __restrict__ kb,
                                             const float* __restrict__ vb,
                                             __bf16* __restrict__ qo,
                                             __bf16* __restrict__ klin,
                                             __bf16* __restrict__ vlin) {
  int bx = blockIdx.x;
  int L = (bx & 7) * 128 + (bx >> 3);  // 1024 % 8 == 0: bijective XCD chunk
  int mb = L >> 1, nh = L & 1;         // nh inner: pair shares x rows on XCD
  int wave = threadIdx.x >> 6, lane = threadIdx.x & 63;
  int g = lane >> 4, c = lane & 15;
  int r0 = mb * 64 + wave * 16;
  const v8bf* wf = (const v8bf*)wfrag;

  v8bf a[8];
#pragma unroll
  for (int kk = 0; kk < 8; ++kk) {
    const float* ap = x + (size_t)(r0 + c) * 256 + kk * 32 + 8 * g;
    float4 f0 = *(const float4*)ap;
    float4 f1 = *(const float4*)(ap + 4);
    v8bf t;
    t[0] = (__bf16)f0.x; t[1] = (__bf16)f0.y; t[2] = (__bf16)f0.z; t[3] = (__bf16)f0.w;
    t[4] = (__bf16)f1.x; t[5] = (__bf16)f1.y; t[6] = (__bf16)f1.z; t[7] = (__bf16)f1.w;
    a[kk] = t;
  }
#pragma unroll
  for (int ni = 0; ni < 3; ++ni) {
    int nb = nh * 3 + ni;
    int n0 = nb * 64;
    f32x4 acc[4];
#pragma unroll
    for (int n = 0; n < 4; ++n) acc[n] = f32x4{0.f, 0.f, 0.f, 0.f};
#pragma unroll
    for (int kk = 0; kk < 8; ++kk) {
      v8bf bf[4];
#pragma unroll
      for (int n = 0; n < 4; ++n)
        bf[n] = wf[(((nb * 8 + kk) * 4 + n) << 6) | lane];
#pragma unroll
      for (int n = 0; n < 4; ++n) acc[n] = MFMA16(a[kk], bf[n], acc[n]);
    }
#pragma unroll
    for (int n = 0; n < 4; ++n) {
      int col = n0 + n * 16 + c;
      float bias;
      if (col < 256) bias = qb[col] * QSCALE;
      else if (col < 320) bias = kb[col - 256];
      else bias = vb[col - 320];
#pragma unroll
      for (int j = 0; j < 4; ++j) {
        int row = r0 + 4 * g + j;
        float v = acc[n][j] + bias;
        if (col < 256) qo[(size_t)row * 256 + col] = (__bf16)v;
        else if (col < 320) klin[(size_t)row * 64 + (col - 256)] = (__bf16)v;
        else vlin[(size_t)row * 64 + (col - 320)] = (__bf16)v;
      }
    }
  }
}

// ---------------- K2: depthwise 3x3 stride-2 conv on k,v ----------------
__global__ __launch_bounds__(256) void k_conv(const __bf16* __restrict__ klin,
                                              const __bf16* __restrict__ vlin,
                                              const float* __restrict__ kw,
                                              const float* __restrict__ kbias,
                                              const float* __restrict__ vw,
                                              const float* __restrict__ vbias,
                                              __bf16* __restrict__ kc,
                                              __bf16* __restrict__ vcT) {
  __shared__ __bf16 VT[32][66];
  int bx = blockIdx.x;
  int b = bx >> 5, pt = bx & 31;
  int t = threadIdx.x;
  int ch = t & 63, pg = t >> 6;
  float kwv[9], vwv[9];
#pragma unroll
  for (int i = 0; i < 9; ++i) { kwv[i] = kw[i * 64 + ch]; vwv[i] = vw[i * 64 + ch]; }
  float kb0 = kbias[ch], vb0 = vbias[ch];
  const __bf16* kin = klin + (size_t)b * 262144;
  const __bf16* vin = vlin + (size_t)b * 262144;
#pragma unroll
  for (int i = 0; i < 8; ++i) {
    int pl = pg * 8 + i;
    int p = pt * 32 + pl;
    int oy = p >> 5, ox = p & 31;
    float ak = kb0, av = vb0;
#pragma unroll
    for (int dy = 0; dy < 3; ++dy) {
      int iy = 2 * oy - 1 + dy;
      if (iy < 0 || iy > 63) continue;
#pragma unroll
      for (int dx = 0; dx < 3; ++dx) {
        int ix = 2 * ox - 1 + dx;
        if (ix < 0 || ix > 63) continue;
        size_t src = ((size_t)iy * 64 + ix) * 64 + ch;
        ak += (float)kin[src] * kwv[dy * 3 + dx];
        av += (float)vin[src] * vwv[dy * 3 + dx];
      }
    }
    kc[((size_t)b * 1024 + p) * 64 + ch] = (__bf16)ak;
    VT[pl][ch] = (__bf16)av;
  }
  __syncthreads();
  int row = t >> 2, c0 = (t & 3) * 8;
  __bf16 tmp[8];
#pragma unroll
  for (int i = 0; i < 8; ++i) tmp[i] = VT[c0 + i][row];
  *(v4i*)(vcT + (size_t)b * 65536 + row * 1024 + pt * 32 + c0) = *(v4i*)tmp;
}

// ---------------- K3: MQA flash attention ----------------
// grid 1024 (XCD-chunked by batch); 4 waves (256 thr), wave = 32 q rows.
// 64-kv double-tile per iter (16 iters): 2 subtiles share one barrier +
// staging phase. Denominator: fp32 partial sums of the exp outputs
// (R7-proven numerics; the bf16 ones-column MFMA version failed absmax).
__global__ __launch_bounds__(256) void k_attn(const __bf16* __restrict__ q,
                                              const __bf16* __restrict__ kc,
                                              const __bf16* __restrict__ vcT,
                                              __bf16* __restrict__ pv) {
  __shared__ __bf16 KV[16384];  // 2 buffers x (K0 K1 V0 V1) x 2048 elems
  int bx = blockIdx.x;
  int L = (bx & 7) * 128 + (bx >> 3);
  int b = L >> 7, hq = L & 127;
  int h = hq >> 5, qg = hq & 31;
  int wave = threadIdx.x >> 6, lane = threadIdx.x & 63;
  int c = lane & 31, hi = lane >> 5;
  int t = threadIdx.x;
  int qtile = qg * 4 + wave;
  size_t rowBase = (size_t)b * 4096 + qtile * 32;

  // staging source pointers (pre-swizzled global, linear LDS dest)
  int kj = t >> 5, kr = (t & 31) ^ kj;
  const __bf16* kg0 = kc + (size_t)b * 65536 + kr * 64 + kj * 8;  // rows 0-31
  const __bf16* kg1 = kg0 + 2048;                                 // rows 32-63
  int dt_ = t >> 7, ks_ = (t >> 6) & 1, vh_ = (t >> 5) & 1;
  int cc = (t & 31) ^ (ks_ * 2 + vh_);
  const __bf16* vg0 = vcT + (size_t)b * 65536 + (size_t)(dt_ * 32 + cc) * 1024 +
                      ks_ * 16 + vh_ * 8;  // kv 0-31
  const __bf16* vg1 = vg0 + 32;            // kv 32-63
  __bf16* kl0 = &KV[t * 8];
  __bf16* kl1 = kl0 + 2048;
  __bf16* vl0 = kl0 + 4096;
  __bf16* vl1 = kl0 + 6144;

  // per-lane fragment read offsets (iter-invariant; s*2048 added inline)
  int Koff[4], Voff[2][2];
#pragma unroll
  for (int kk = 0; kk < 4; ++kk) {
    int j = kk * 2 + hi;
    Koff[kk] = (j * 32 + (c ^ j)) * 8;
  }
#pragma unroll
  for (int ks = 0; ks < 2; ++ks)
#pragma unroll
    for (int dt = 0; dt < 2; ++dt) {
      int j = ks * 2 + hi;
      Voff[ks][dt] = (512 + dt * 128 + ks * 64 + hi * 32 + (c ^ j)) * 8;
    }

  const __bf16* qbase = q + (rowBase + c) * 256 + h * 64 + hi * 8;
  v8bf Qf[4];
#pragma unroll
  for (int kk = 0; kk < 4; ++kk) Qf[kk] = *(const v8bf*)(qbase + kk * 16);

  f32x16 O0 = {}, O1 = {};
  const f32x16 Z16 = {};
  float ls0 = 0.f, ls1 = 0.f, ls2 = 0.f, ls3 = 0.f;

  GLOAD16(kg0, kl0);
  GLOAD16(kg1, kl1);
  GLOAD16(vg0, vl0);
  GLOAD16(vg1, vl1);
  __syncthreads();

  int buf = 0;
  for (int it = 0; it < 16; ++it) {
    const __bf16* base = &KV[buf * 8192];

    if (it < 15) {
      int nb = buf ^ 1;
      int ko = (it + 1) * 4096, vo = (it + 1) * 64;
      GLOAD16(kg0 + ko, kl0 + nb * 8192);
      GLOAD16(kg1 + ko, kl1 + nb * 8192);
      GLOAD16(vg0 + vo, vl0 + nb * 8192);
      GLOAD16(vg1 + vo, vl1 + nb * 8192);
    }

#pragma unroll
    for (int s = 0; s < 2; ++s) {
      v8bf Kf[4];
#pragma unroll
      for (int kk = 0; kk < 4; ++kk)
        Kf[kk] = *(const v8bf*)(base + s * 2048 + Koff[kk]);
      f32x16 S = MFMA32(Kf[0], Qf[0], Z16);
      S = MFMA32(Kf[1], Qf[1], S);
      S = MFMA32(Kf[2], Qf[2], S);
      S = MFMA32(Kf[3], Qf[3], S);

      // exp2-direct (Q pre-scaled by log2(e)); fp32 partial sums (R7 path)
#pragma unroll
      for (int r = 0; r < 16; ++r) S[r] = __builtin_amdgcn_exp2f(S[r]);
      ls0 += (S[0] + S[1]) + (S[2] + S[3]);
      ls1 += (S[4] + S[5]) + (S[6] + S[7]);
      ls2 += (S[8] + S[9]) + (S[10] + S[11]);
      ls3 += (S[12] + S[13]) + (S[14] + S[15]);

      int w[8];
#pragma unroll
      for (int q2 = 0; q2 < 8; ++q2) {
        int r;
        asm("v_cvt_pk_bf16_f32 %0, %1, %2"
            : "=v"(r) : "v"(S[2 * q2]), "v"(S[2 * q2 + 1]));
        w[q2] = r;
      }
      v2i s1 = __builtin_amdgcn_permlane32_swap(w[2], w[0], false, false);
      v2i s2 = __builtin_amdgcn_permlane32_swap(w[3], w[1], false, false);
      v2i s3 = __builtin_amdgcn_permlane32_swap(w[6], w[4], false, false);
      v2i s4 = __builtin_amdgcn_permlane32_swap(w[7], w[5], false, false);
      v4i pa0i, pa1i;
      pa0i[0] = s1[1]; pa0i[1] = s2[1]; pa0i[2] = s1[0]; pa0i[3] = s2[0];
      pa1i[0] = s3[1]; pa1i[1] = s4[1]; pa1i[2] = s3[0]; pa1i[3] = s4[0];
      v8bf pa0 = *(v8bf*)&pa0i, pa1 = *(v8bf*)&pa1i;

      v8bf Vf[2][2];
#pragma unroll
      for (int ks = 0; ks < 2; ++ks)
#pragma unroll
        for (int dt = 0; dt < 2; ++dt)
          Vf[ks][dt] = *(const v8bf*)(base + s * 2048 + Voff[ks][dt]);

      O0 = MFMA32(pa0, Vf[0][0], O0);
      O1 = MFMA32(pa0, Vf[0][1], O1);
      O0 = MFMA32(pa1, Vf[1][0], O0);
      O1 = MFMA32(pa1, Vf[1][1], O1);
    }

    __syncthreads();  // staging for it+1 drained; all waves done with buf
    buf ^= 1;
  }

  // lane (c,hi) holds half the kv rows for q=c; xor(32) adds the other half
  float lsum = (ls0 + ls1) + (ls2 + ls3);
  float tot = lsum + __shfl_xor(lsum, 32);
  float linv = 1.0f / tot;  // lane c holds 1/l for q-row c
  __bf16* op = pv + rowBase * 256 + h * 64;
#pragma unroll
  for (int r = 0; r < 16; ++r) {
    int qr = (r & 3) + 8 * (r >> 2) + 4 * hi;
    float li = __shfl(linv, qr);
    op[(size_t)qr * 256 + c] = (__bf16)(O0[r] * li);
    op[(size_t)qr * 256 + 32 + c] = (__bf16)(O1[r] * li);
  }
}

// ---------------- K4: output projection GEMM ----------------
// M=32768, N=256, K=256. grid 1024 = 512 mb x 2 nh (2 N-tiles each);
// dense fragment-ordered B loads.
__global__ __launch_bounds__(256) void k_out(const __bf16* __restrict__ pvb,
                                             const __bf16* __restrict__ owfrag,
                                             const float* __restrict__ ob,
                                             float* __restrict__ out) {
  int bx = blockIdx.x;
  int L = (bx & 7) * 128 + (bx >> 3);
  int mb = L >> 1, nh = L & 1;
  int wave = threadIdx.x >> 6, lane = threadIdx.x & 63;
  int g = lane >> 4, c = lane & 15;
  int r0 = mb * 64 + wave * 16;
  const v8bf* wf = (const v8bf*)owfrag;

  v8bf a[8];
#pragma unroll
  for (int kk = 0; kk < 8; ++kk)
    a[kk] = *(const v8bf*)(pvb + (size_t)(r0 + c) * 256 + kk * 32 + 8 * g);
#pragma unroll
  for (int ni = 0; ni < 2; ++ni) {
    int nb = nh * 2 + ni;
    int n0 = nb * 64;
    f32x4 acc[4];
#pragma unroll
    for (int n = 0; n < 4; ++n) acc[n] = f32x4{0.f, 0.f, 0.f, 0.f};
#pragma unroll
    for (int kk = 0; kk < 8; ++kk) {
      v8bf bf[4];
#pragma unroll
      for (int n = 0; n < 4; ++n)
        bf[n] = wf[(((nb * 8 + kk) * 4 + n) << 6) | lane];
#pragma unroll
      for (int n = 0; n < 4; ++n) acc[n] = MFMA16(a[kk], bf[n], acc[n]);
    }
#pragma unroll
    for (int n = 0; n < 4; ++n) {
      int col = n0 + n * 16 + c;
      float bias = ob[col];
#pragma unroll
      for (int j = 0; j < 4; ++j) {
        int row = r0 + 4 * g + j;
        out[(size_t)row * 256 + col] = acc[n][j] + bias;
      }
    }
  }
}

// ---------------- launcher ----------------
extern "C" void kernel_launch(void* const* d_in, const int* in_sizes, int n_in,
                              void* d_out, int out_size, void* d_ws, size_t ws_size,
                              hipStream_t stream) {
  const float* x   = (const float*)d_in[0];
  const float* qw  = (const float*)d_in[1];
  const float* qb  = (const float*)d_in[2];
  const float* kw  = (const float*)d_in[3];
  const float* kb  = (const float*)d_in[4];
  const float* vw  = (const float*)d_in[5];
  const float* vb  = (const float*)d_in[6];
  const float* kcw = (const float*)d_in[7];
  const float* kcb = (const float*)d_in[8];
  const float* vcw = (const float*)d_in[9];
  const float* vcb = (const float*)d_in[10];
  const float* ow  = (const float*)d_in[11];
  const float* ob  = (const float*)d_in[12];
  float* out = (float*)d_out;
  char* ws = (char*)d_ws;

  __bf16* pv     = (__bf16*)(ws + 0);          // 16,777,216
  __bf16* qbuf   = (__bf16*)(ws + 16777216);   // 16,777,216
  __bf16* klin   = (__bf16*)(ws + 33554432);   //  4,194,304
  __bf16* vlin   = (__bf16*)(ws + 37748736);   //  4,194,304
  __bf16* kc     = (__bf16*)(ws + 41943040);   //  1,048,576
  __bf16* vcT    = (__bf16*)(ws + 42991616);   //  1,048,576
  __bf16* wfrag  = (__bf16*)(ws + 44040192);   //    196,608
  __bf16* owfrag = (__bf16*)(ws + 44236800);   //    131,072

  k_cvt_w<<<640, 256, 0, stream>>>(qw, kw, vw, ow, wfrag, owfrag);
  k_qkv<<<1024, 256, 0, stream>>>(x, wfrag, qb, kb, vb, qbuf, klin, vlin);
  k_conv<<<256, 256, 0, stream>>>(klin, vlin, kcw, kcb, vcw, vcb, kc, vcT);
  k_attn<<<1024, 256, 0, stream>>>(qbuf, kc, vcT, pv);
  k_out<<<1024, 256, 0, stream>>>(pv, owfrag, ob, out);
}

// Round 10
// 107.082 us; speedup vs baseline: 1.0142x; 1.0142x over previous
//
#include <hip/hip_runtime.h>
#include <hip/hip_bf16.h>

typedef __bf16 v8bf __attribute__((ext_vector_type(8)));
typedef float f32x4 __attribute__((ext_vector_type(4)));
typedef float f32x16 __attribute__((ext_vector_type(16)));
typedef int v2i __attribute__((ext_vector_type(2)));
typedef int v4i __attribute__((ext_vector_type(4)));

#define MFMA16(a, b, c) __builtin_amdgcn_mfma_f32_16x16x32_bf16(a, b, c, 0, 0, 0)
#define MFMA32(a, b, c) __builtin_amdgcn_mfma_f32_32x32x16_bf16(a, b, c, 0, 0, 0)
#define GLOAD16(gp, lp)                                                        \
  __builtin_amdgcn_global_load_lds(                                            \
      (const __attribute__((address_space(1))) void*)(gp),                     \
      (__attribute__((address_space(3))) void*)(lp), 16, 0, 0)

// q scale = SCALE * log2(e) so that exp2(qk) == exp(qk*SCALE)
#define QSCALE 0.18033688011112042f

// ---------------- K0: weights -> MFMA-fragment-ordered bf16 ----------------
// wfrag[nb(6)][kk(8)][n(4)][lane(64)][8]: lane(g=l>>4,c=l&15) holds
//   wT row nb*64+n*16+c, cols kk*32+8g..+7  (wT = W^T; q part pre-scaled)
// owfrag[nb(4)][kk(8)][n(4)][lane][8] likewise for out_w^T.
__global__ __launch_bounds__(256) void k_cvt_w(const float* __restrict__ qw,
                                               const float* __restrict__ kw,
                                               const float* __restrict__ vw,
                                               const float* __restrict__ ow,
                                               __bf16* __restrict__ wfrag,
                                               __bf16* __restrict__ owfrag) {
  int t = blockIdx.x * 256 + threadIdx.x;  // 640*256 = 163840
  if (t < 98304) {
    int e = t & 7, idx = t >> 3;
    int l = idx & 63; idx >>= 6;
    int n = idx & 3; idx >>= 2;
    int kk = idx & 7, nb = idx >> 3;
    int nn = nb * 64 + n * 16 + (l & 15);
    int k = kk * 32 + 8 * (l >> 4) + e;
    float v;
    if (nn < 256) v = qw[k * 256 + nn] * QSCALE;
    else if (nn < 320) v = kw[k * 64 + (nn - 256)];
    else v = vw[k * 64 + (nn - 320)];
    wfrag[t] = (__bf16)v;
  } else {
    int u = t - 98304;
    int e = u & 7, idx = u >> 3;
    int l = idx & 63; idx >>= 6;
    int n = idx & 3; idx >>= 2;
    int kk = idx & 7, nb = idx >> 3;
    int nn = nb * 64 + n * 16 + (l & 15);
    int k = kk * 32 + 8 * (l >> 4) + e;
    owfrag[u] = (__bf16)ow[k * 256 + nn];
  }
}

// ---------------- K1: fused QKV projection GEMM, x read ONCE --------------
// M=32768, N=384, K=256. grid 512 m-tiles (BM=64, wave=16 rows); A-frags in
// registers (fp32 x -> bf16); 6 N-tiles reuse them; dense wfrag B-loads.
__global__ __launch_bounds__(256) void k_qkv(const float* __restrict__ x,
                                             const __bf16* __restrict__ wfrag,
                                             const float* __restrict__ qb,
                                             const float* __restrict__ kb,
                                             const float* __restrict__ vb,
                                             __bf16* __restrict__ qo,
                                             __bf16* __restrict__ klin,
                                             __bf16* __restrict__ vlin) {
  int bx = blockIdx.x;
  int mb = (bx & 7) * 64 + (bx >> 3);  // 512 % 8 == 0: bijective XCD chunk
  int wave = threadIdx.x >> 6, lane = threadIdx.x & 63;
  int g = lane >> 4, c = lane & 15;
  int r0 = mb * 64 + wave * 16;
  const v8bf* wf = (const v8bf*)wfrag;

  v8bf a[8];
#pragma unroll
  for (int kk = 0; kk < 8; ++kk) {
    const float* ap = x + (size_t)(r0 + c) * 256 + kk * 32 + 8 * g;
    float4 f0 = *(const float4*)ap;
    float4 f1 = *(const float4*)(ap + 4);
    v8bf t;
    t[0] = (__bf16)f0.x; t[1] = (__bf16)f0.y; t[2] = (__bf16)f0.z; t[3] = (__bf16)f0.w;
    t[4] = (__bf16)f1.x; t[5] = (__bf16)f1.y; t[6] = (__bf16)f1.z; t[7] = (__bf16)f1.w;
    a[kk] = t;
  }
#pragma unroll
  for (int nb = 0; nb < 6; ++nb) {
    int n0 = nb * 64;
    f32x4 acc[4];
#pragma unroll
    for (int n = 0; n < 4; ++n) acc[n] = f32x4{0.f, 0.f, 0.f, 0.f};
#pragma unroll
    for (int kk = 0; kk < 8; ++kk) {
      v8bf bf[4];
#pragma unroll
      for (int n = 0; n < 4; ++n)
        bf[n] = wf[(((nb * 8 + kk) * 4 + n) << 6) | lane];
#pragma unroll
      for (int n = 0; n < 4; ++n) acc[n] = MFMA16(a[kk], bf[n], acc[n]);
    }
#pragma unroll
    for (int n = 0; n < 4; ++n) {
      int col = n0 + n * 16 + c;
      float bias;
      if (col < 256) bias = qb[col] * QSCALE;
      else if (col < 320) bias = kb[col - 256];
      else bias = vb[col - 320];
#pragma unroll
      for (int j = 0; j < 4; ++j) {
        int row = r0 + 4 * g + j;
        float v = acc[n][j] + bias;
        if (col < 256) qo[(size_t)row * 256 + col] = (__bf16)v;
        else if (col < 320) klin[(size_t)row * 64 + (col - 256)] = (__bf16)v;
        else vlin[(size_t)row * 64 + (col - 320)] = (__bf16)v;
      }
    }
  }
}

// ---------------- K2: depthwise 3x3 stride-2 conv on k,v ----------------
__global__ __launch_bounds__(256) void k_conv(const __bf16* __restrict__ klin,
                                              const __bf16* __restrict__ vlin,
                                              const float* __restrict__ kw,
                                              const float* __restrict__ kbias,
                                              const float* __restrict__ vw,
                                              const float* __restrict__ vbias,
                                              __bf16* __restrict__ kc,
                                              __bf16* __restrict__ vcT) {
  __shared__ __bf16 VT[32][66];
  int bx = blockIdx.x;
  int b = bx >> 5, pt = bx & 31;
  int t = threadIdx.x;
  int ch = t & 63, pg = t >> 6;
  float kwv[9], vwv[9];
#pragma unroll
  for (int i = 0; i < 9; ++i) { kwv[i] = kw[i * 64 + ch]; vwv[i] = vw[i * 64 + ch]; }
  float kb0 = kbias[ch], vb0 = vbias[ch];
  const __bf16* kin = klin + (size_t)b * 262144;
  const __bf16* vin = vlin + (size_t)b * 262144;
#pragma unroll
  for (int i = 0; i < 8; ++i) {
    int pl = pg * 8 + i;
    int p = pt * 32 + pl;
    int oy = p >> 5, ox = p & 31;
    float ak = kb0, av = vb0;
#pragma unroll
    for (int dy = 0; dy < 3; ++dy) {
      int iy = 2 * oy - 1 + dy;
      if (iy < 0 || iy > 63) continue;
#pragma unroll
      for (int dx = 0; dx < 3; ++dx) {
        int ix = 2 * ox - 1 + dx;
        if (ix < 0 || ix > 63) continue;
        size_t src = ((size_t)iy * 64 + ix) * 64 + ch;
        ak += (float)kin[src] * kwv[dy * 3 + dx];
        av += (float)vin[src] * vwv[dy * 3 + dx];
      }
    }
    kc[((size_t)b * 1024 + p) * 64 + ch] = (__bf16)ak;
    VT[pl][ch] = (__bf16)av;
  }
  __syncthreads();
  int row = t >> 2, c0 = (t & 3) * 8;
  __bf16 tmp[8];
#pragma unroll
  for (int i = 0; i < 8; ++i) tmp[i] = VT[c0 + i][row];
  *(v4i*)(vcT + (size_t)b * 65536 + row * 1024 + pt * 32 + c0) = *(v4i*)tmp;
}

// ---------------- K3: MQA flash attention + fused out-projection ----------
// grid 1024 = 8 b x 128 qtiles (XCD-chunked by batch); 4 waves = the 4 HEADS
// of the same 32 q rows. Attn loop = R7 core verbatim (32-kv tiles, 16KB
// LDS dbuf, exp2-direct, fp32 partial sums). Epilogue: O -> LDS (union with
// dead KV buffer), barrier, each wave runs the old k_out inner loop for its
// 64 out-cols (bit-identical op order) and stores fp32 + bias.
__global__ __launch_bounds__(256) void k_attn(const __bf16* __restrict__ q,
                                              const __bf16* __restrict__ kc,
                                              const __bf16* __restrict__ vcT,
                                              const __bf16* __restrict__ owfrag,
                                              const float* __restrict__ ob,
                                              float* __restrict__ out) {
  __shared__ __bf16 SMEM[8448];  // KV dbuf (8192) / Otile[32][264] union
  int bx = blockIdx.x;
  int L = (bx & 7) * 128 + (bx >> 3);
  int b = L >> 7, qt = L & 127;
  int wave = threadIdx.x >> 6, lane = threadIdx.x & 63;  // wave == head
  int c = lane & 31, hi = lane >> 5;
  int t = threadIdx.x;
  size_t rowBase = (size_t)b * 4096 + qt * 32;

  // staging source pointers (pre-swizzled global, linear LDS dest)
  int kj = t >> 5, kr = (t & 31) ^ kj;
  const __bf16* kg = kc + (size_t)b * 65536 + kr * 64 + kj * 8;
  int dt_ = t >> 7, ks_ = (t >> 6) & 1, vh_ = (t >> 5) & 1;
  int cc = (t & 31) ^ (ks_ * 2 + vh_);
  const __bf16* vg = vcT + (size_t)b * 65536 + (size_t)(dt_ * 32 + cc) * 1024 +
                     ks_ * 16 + vh_ * 8;
  __bf16* kl = &SMEM[t * 8];
  __bf16* vl = &SMEM[2048 + t * 8];

  int Koff[4], Voff[2][2];
#pragma unroll
  for (int kk = 0; kk < 4; ++kk) {
    int j = kk * 2 + hi;
    Koff[kk] = (j * 32 + (c ^ j)) * 8;
  }
#pragma unroll
  for (int ks = 0; ks < 2; ++ks)
#pragma unroll
    for (int dt = 0; dt < 2; ++dt) {
      int j = ks * 2 + hi;
      Voff[ks][dt] = (256 + dt * 128 + ks * 64 + hi * 32 + (c ^ j)) * 8;
    }

  const __bf16* qbase = q + (rowBase + c) * 256 + wave * 64 + hi * 8;
  v8bf Qf[4];
#pragma unroll
  for (int kk = 0; kk < 4; ++kk) Qf[kk] = *(const v8bf*)(qbase + kk * 16);

  f32x16 O0 = {}, O1 = {};
  const f32x16 Z16 = {};
  float ls0 = 0.f, ls1 = 0.f, ls2 = 0.f, ls3 = 0.f;

  GLOAD16(kg, kl);
  GLOAD16(vg, vl);
  __syncthreads();

  int buf = 0;
  for (int it = 0; it < 32; ++it) {
    const __bf16* base = &SMEM[buf * 4096];
    v8bf Kf[4], Vf[2][2];
#pragma unroll
    for (int kk = 0; kk < 4; ++kk) Kf[kk] = *(const v8bf*)(base + Koff[kk]);
#pragma unroll
    for (int ks = 0; ks < 2; ++ks)
#pragma unroll
      for (int dt = 0; dt < 2; ++dt)
        Vf[ks][dt] = *(const v8bf*)(base + Voff[ks][dt]);

    if (it < 31) {
      int nb = buf ^ 1;
      GLOAD16(kg + (it + 1) * 2048, kl + nb * 4096);
      GLOAD16(vg + (it + 1) * 32, vl + nb * 4096);
    }

    f32x16 S = MFMA32(Kf[0], Qf[0], Z16);
    S = MFMA32(Kf[1], Qf[1], S);
    S = MFMA32(Kf[2], Qf[2], S);
    S = MFMA32(Kf[3], Qf[3], S);

    // exp2-direct (Q pre-scaled by log2(e)); fp32 tree partial sums
#pragma unroll
    for (int r = 0; r < 16; ++r) S[r] = __builtin_amdgcn_exp2f(S[r]);
    ls0 += (S[0] + S[1]) + (S[2] + S[3]);
    ls1 += (S[4] + S[5]) + (S[6] + S[7]);
    ls2 += (S[8] + S[9]) + (S[10] + S[11]);
    ls3 += (S[12] + S[13]) + (S[14] + S[15]);

    int w[8];
#pragma unroll
    for (int q2 = 0; q2 < 8; ++q2) {
      int r;
      asm("v_cvt_pk_bf16_f32 %0, %1, %2"
          : "=v"(r) : "v"(S[2 * q2]), "v"(S[2 * q2 + 1]));
      w[q2] = r;
    }
    v2i s1 = __builtin_amdgcn_permlane32_swap(w[2], w[0], false, false);
    v2i s2 = __builtin_amdgcn_permlane32_swap(w[3], w[1], false, false);
    v2i s3 = __builtin_amdgcn_permlane32_swap(w[6], w[4], false, false);
    v2i s4 = __builtin_amdgcn_permlane32_swap(w[7], w[5], false, false);
    v4i pa0i, pa1i;
    pa0i[0] = s1[1]; pa0i[1] = s2[1]; pa0i[2] = s1[0]; pa0i[3] = s2[0];
    pa1i[0] = s3[1]; pa1i[1] = s4[1]; pa1i[2] = s3[0]; pa1i[3] = s4[0];
    v8bf pa0 = *(v8bf*)&pa0i, pa1 = *(v8bf*)&pa1i;

    O0 = MFMA32(pa0, Vf[0][0], O0);
    O1 = MFMA32(pa0, Vf[0][1], O1);
    O0 = MFMA32(pa1, Vf[1][0], O0);
    O1 = MFMA32(pa1, Vf[1][1], O1);

    __syncthreads();  // staging for it+1 drained; all waves done with buf
    buf ^= 1;
  }
  // after the final barrier every wave is done reading KV -> union is free

  float lsum = (ls0 + ls1) + (ls2 + ls3);
  float tot = lsum + __shfl_xor(lsum, 32);
  float linv = 1.0f / tot;  // lane c holds 1/l for q-row c

  // normalized O (bf16, same rounding as the old pv store) -> LDS
  __bf16(*Ot)[264] = (__bf16(*)[264])SMEM;
#pragma unroll
  for (int r = 0; r < 16; ++r) {
    int qr = (r & 3) + 8 * (r >> 2) + 4 * hi;
    float li = __shfl(linv, qr);
    Ot[qr][wave * 64 + c] = (__bf16)(O0[r] * li);
    Ot[qr][wave * 64 + 32 + c] = (__bf16)(O1[r] * li);
  }
  __syncthreads();

  // out-projection: wave handles out-cols n0 = wave*64 (old k_out inner loop)
  int g = lane >> 4, c16 = lane & 15;
  const v8bf* wf = (const v8bf*)owfrag;
  f32x4 acc[2][4];
#pragma unroll
  for (int m = 0; m < 2; ++m)
#pragma unroll
    for (int n = 0; n < 4; ++n) acc[m][n] = f32x4{0.f, 0.f, 0.f, 0.f};
#pragma unroll
  for (int kk = 0; kk < 8; ++kk) {
    v8bf a0 = *(const v8bf*)&Ot[c16][kk * 32 + 8 * g];
    v8bf a1 = *(const v8bf*)&Ot[16 + c16][kk * 32 + 8 * g];
    v8bf bf[4];
#pragma unroll
    for (int n = 0; n < 4; ++n)
      bf[n] = wf[(((wave * 8 + kk) * 4 + n) << 6) | lane];
#pragma unroll
    for (int n = 0; n < 4; ++n) {
      acc[0][n] = MFMA16(a0, bf[n], acc[0][n]);
      acc[1][n] = MFMA16(a1, bf[n], acc[1][n]);
    }
  }
#pragma unroll
  for (int n = 0; n < 4; ++n) {
    int col = wave * 64 + n * 16 + c16;
    float bias = ob[col];
#pragma unroll
    for (int m = 0; m < 2; ++m)
#pragma unroll
      for (int j = 0; j < 4; ++j) {
        int row = m * 16 + 4 * g + j;
        out[(rowBase + row) * 256 + col] = acc[m][n][j] + bias;
      }
  }
}

// ---------------- launcher ----------------
extern "C" void kernel_launch(void* const* d_in, const int* in_sizes, int n_in,
                              void* d_out, int out_size, void* d_ws, size_t ws_size,
                              hipStream_t stream) {
  const float* x   = (const float*)d_in[0];
  const float* qw  = (const float*)d_in[1];
  const float* qb  = (const float*)d_in[2];
  const float* kw  = (const float*)d_in[3];
  const float* kb  = (const float*)d_in[4];
  const float* vw  = (const float*)d_in[5];
  const float* vb  = (const float*)d_in[6];
  const float* kcw = (const float*)d_in[7];
  const float* kcb = (const float*)d_in[8];
  const float* vcw = (const float*)d_in[9];
  const float* vcb = (const float*)d_in[10];
  const float* ow  = (const float*)d_in[11];
  const float* ob  = (const float*)d_in[12];
  float* out = (float*)d_out;
  char* ws = (char*)d_ws;

  __bf16* qbuf   = (__bf16*)(ws + 16777216);   // 16,777,216
  __bf16* klin   = (__bf16*)(ws + 33554432);   //  4,194,304
  __bf16* vlin   = (__bf16*)(ws + 37748736);   //  4,194,304
  __bf16* kc     = (__bf16*)(ws + 41943040);   //  1,048,576
  __bf16* vcT    = (__bf16*)(ws + 42991616);   //  1,048,576
  __bf16* wfrag  = (__bf16*)(ws + 44040192);   //    196,608
  __bf16* owfrag = (__bf16*)(ws + 44236800);   //    131,072

  k_cvt_w<<<640, 256, 0, stream>>>(qw, kw, vw, ow, wfrag, owfrag);
  k_qkv<<<512, 256, 0, stream>>>(x, wfrag, qb, kb, vb, qbuf, klin, vlin);
  k_conv<<<256, 256, 0, stream>>>(klin, vlin, kcw, kcb, vcw, vcb, kc, vcT);
  k_attn<<<1024, 256, 0, stream>>>(qbuf, kc, vcT, owfrag, ob, out);
}

// Round 11
// 96.678 us; speedup vs baseline: 1.1234x; 1.1076x over previous
//
#include <hip/hip_runtime.h>
#include <hip/hip_bf16.h>

typedef __bf16 v8bf __attribute__((ext_vector_type(8)));
typedef float f32x4 __attribute__((ext_vector_type(4)));
typedef float f32x16 __attribute__((ext_vector_type(16)));
typedef int v2i __attribute__((ext_vector_type(2)));
typedef int v4i __attribute__((ext_vector_type(4)));

#define MFMA16(a, b, c) __builtin_amdgcn_mfma_f32_16x16x32_bf16(a, b, c, 0, 0, 0)
#define MFMA32(a, b, c) __builtin_amdgcn_mfma_f32_32x32x16_bf16(a, b, c, 0, 0, 0)
#define GLOAD16(gp, lp)                                                        \
  __builtin_amdgcn_global_load_lds(                                            \
      (const __attribute__((address_space(1))) void*)(gp),                     \
      (__attribute__((address_space(3))) void*)(lp), 16, 0, 0)

// q scale = SCALE * log2(e) so that exp2(qk) == exp(qk*SCALE)
#define QSCALE 0.18033688011112042f

// ---------------- K0: weights -> MFMA-fragment-ordered bf16 ----------------
__global__ __launch_bounds__(256) void k_cvt_w(const float* __restrict__ qw,
                                               const float* __restrict__ kw,
                                               const float* __restrict__ vw,
                                               const float* __restrict__ ow,
                                               __bf16* __restrict__ wfrag,
                                               __bf16* __restrict__ owfrag) {
  int t = blockIdx.x * 256 + threadIdx.x;  // 640*256 = 163840
  if (t < 98304) {
    int e = t & 7, idx = t >> 3;
    int l = idx & 63; idx >>= 6;
    int n = idx & 3; idx >>= 2;
    int kk = idx & 7, nb = idx >> 3;
    int nn = nb * 64 + n * 16 + (l & 15);
    int k = kk * 32 + 8 * (l >> 4) + e;
    float v;
    if (nn < 256) v = qw[k * 256 + nn] * QSCALE;
    else if (nn < 320) v = kw[k * 64 + (nn - 256)];
    else v = vw[k * 64 + (nn - 320)];
    wfrag[t] = (__bf16)v;
  } else {
    int u = t - 98304;
    int e = u & 7, idx = u >> 3;
    int l = idx & 63; idx >>= 6;
    int n = idx & 3; idx >>= 2;
    int kk = idx & 7, nb = idx >> 3;
    int nn = nb * 64 + n * 16 + (l & 15);
    int k = kk * 32 + 8 * (l >> 4) + e;
    owfrag[u] = (__bf16)ow[k * 256 + nn];
  }
}

// ---------------- K1: fused QKV projection GEMM, x read ONCE --------------
__global__ __launch_bounds__(256) void k_qkv(const float* __restrict__ x,
                                             const __bf16* __restrict__ wfrag,
                                             const float* __restrict__ qb,
                                             const float* __restrict__ kb,
                                             const float* __restrict__ vb,
                                             __bf16* __restrict__ qo,
                                             __bf16* __restrict__ klin,
                                             __bf16* __restrict__ vlin) {
  int bx = blockIdx.x;
  int mb = (bx & 7) * 64 + (bx >> 3);  // 512 % 8 == 0: bijective XCD chunk
  int wave = threadIdx.x >> 6, lane = threadIdx.x & 63;
  int g = lane >> 4, c = lane & 15;
  int r0 = mb * 64 + wave * 16;
  const v8bf* wf = (const v8bf*)wfrag;

  v8bf a[8];
#pragma unroll
  for (int kk = 0; kk < 8; ++kk) {
    const float* ap = x + (size_t)(r0 + c) * 256 + kk * 32 + 8 * g;
    float4 f0 = *(const float4*)ap;
    float4 f1 = *(const float4*)(ap + 4);
    v8bf t;
    t[0] = (__bf16)f0.x; t[1] = (__bf16)f0.y; t[2] = (__bf16)f0.z; t[3] = (__bf16)f0.w;
    t[4] = (__bf16)f1.x; t[5] = (__bf16)f1.y; t[6] = (__bf16)f1.z; t[7] = (__bf16)f1.w;
    a[kk] = t;
  }
#pragma unroll
  for (int nb = 0; nb < 6; ++nb) {
    int n0 = nb * 64;
    f32x4 acc[4];
#pragma unroll
    for (int n = 0; n < 4; ++n) acc[n] = f32x4{0.f, 0.f, 0.f, 0.f};
#pragma unroll
    for (int kk = 0; kk < 8; ++kk) {
      v8bf bf[4];
#pragma unroll
      for (int n = 0; n < 4; ++n)
        bf[n] = wf[(((nb * 8 + kk) * 4 + n) << 6) | lane];
#pragma unroll
      for (int n = 0; n < 4; ++n) acc[n] = MFMA16(a[kk], bf[n], acc[n]);
    }
#pragma unroll
    for (int n = 0; n < 4; ++n) {
      int col = n0 + n * 16 + c;
      float bias;
      if (col < 256) bias = qb[col] * QSCALE;
      else if (col < 320) bias = kb[col - 256];
      else bias = vb[col - 320];
#pragma unroll
      for (int j = 0; j < 4; ++j) {
        int row = r0 + 4 * g + j;
        float v = acc[n][j] + bias;
        if (col < 256) qo[(size_t)row * 256 + col] = (__bf16)v;
        else if (col < 320) klin[(size_t)row * 64 + (col - 256)] = (__bf16)v;
        else vlin[(size_t)row * 64 + (col - 320)] = (__bf16)v;
      }
    }
  }
}

// ---------------- K2: depthwise 3x3 stride-2 conv on k,v ----------------
__global__ __launch_bounds__(256) void k_conv(const __bf16* __restrict__ klin,
                                              const __bf16* __restrict__ vlin,
                                              const float* __restrict__ kw,
                                              const float* __restrict__ kbias,
                                              const float* __restrict__ vw,
                                              const float* __restrict__ vbias,
                                              __bf16* __restrict__ kc,
                                              __bf16* __restrict__ vcT) {
  __shared__ __bf16 VT[32][66];
  int bx = blockIdx.x;
  int b = bx >> 5, pt = bx & 31;
  int t = threadIdx.x;
  int ch = t & 63, pg = t >> 6;
  float kwv[9], vwv[9];
#pragma unroll
  for (int i = 0; i < 9; ++i) { kwv[i] = kw[i * 64 + ch]; vwv[i] = vw[i * 64 + ch]; }
  float kb0 = kbias[ch], vb0 = vbias[ch];
  const __bf16* kin = klin + (size_t)b * 262144;
  const __bf16* vin = vlin + (size_t)b * 262144;
#pragma unroll
  for (int i = 0; i < 8; ++i) {
    int pl = pg * 8 + i;
    int p = pt * 32 + pl;
    int oy = p >> 5, ox = p & 31;
    float ak = kb0, av = vb0;
#pragma unroll
    for (int dy = 0; dy < 3; ++dy) {
      int iy = 2 * oy - 1 + dy;
      if (iy < 0 || iy > 63) continue;
#pragma unroll
      for (int dx = 0; dx < 3; ++dx) {
        int ix = 2 * ox - 1 + dx;
        if (ix < 0 || ix > 63) continue;
        size_t src = ((size_t)iy * 64 + ix) * 64 + ch;
        ak += (float)kin[src] * kwv[dy * 3 + dx];
        av += (float)vin[src] * vwv[dy * 3 + dx];
      }
    }
    kc[((size_t)b * 1024 + p) * 64 + ch] = (__bf16)ak;
    VT[pl][ch] = (__bf16)av;
  }
  __syncthreads();
  int row = t >> 2, c0 = (t & 3) * 8;
  __bf16 tmp[8];
#pragma unroll
  for (int i = 0; i < 8; ++i) tmp[i] = VT[c0 + i][row];
  *(v4i*)(vcT + (size_t)b * 65536 + row * 1024 + pt * 32 + c0) = *(v4i*)tmp;
}

// ---------------- K3: MQA flash attention + fused out-projection ----------
// grid 1024 = 8 b x 128 qtiles; 4 waves = 4 heads of the same 32 q rows.
// Counted-vmcnt 3-buffer pipeline (T3/T4): stage tile it+2, wait own
// vmcnt(4), raw s_barrier (no drain) -> tile it visible; loads for it+1/it+2
// stay in flight across the barrier. Arithmetic identical to R9/R10.
__global__ __launch_bounds__(256) void k_attn(const __bf16* __restrict__ q,
                                              const __bf16* __restrict__ kc,
                                              const __bf16* __restrict__ vcT,
                                              const __bf16* __restrict__ owfrag,
                                              const float* __restrict__ ob,
                                              float* __restrict__ out) {
  __shared__ __bf16 SMEM[12288];  // 3 bufs x (K 2048 + V 2048) / Ot[32][264]
  int bx = blockIdx.x;
  int L = (bx & 7) * 128 + (bx >> 3);
  int b = L >> 7, qt = L & 127;
  int wave = threadIdx.x >> 6, lane = threadIdx.x & 63;  // wave == head
  int c = lane & 31, hi = lane >> 5;
  int t = threadIdx.x;
  size_t rowBase = (size_t)b * 4096 + qt * 32;

  // staging source pointers (pre-swizzled global, linear LDS dest)
  int kj = t >> 5, kr = (t & 31) ^ kj;
  const __bf16* kg = kc + (size_t)b * 65536 + kr * 64 + kj * 8;
  int dt_ = t >> 7, ks_ = (t >> 6) & 1, vh_ = (t >> 5) & 1;
  int cc = (t & 31) ^ (ks_ * 2 + vh_);
  const __bf16* vg = vcT + (size_t)b * 65536 + (size_t)(dt_ * 32 + cc) * 1024 +
                     ks_ * 16 + vh_ * 8;
  __bf16* kl = &SMEM[t * 8];
  __bf16* vl = &SMEM[2048 + t * 8];

  int Koff[4], Voff[2][2];
#pragma unroll
  for (int kk = 0; kk < 4; ++kk) {
    int j = kk * 2 + hi;
    Koff[kk] = (j * 32 + (c ^ j)) * 8;
  }
#pragma unroll
  for (int ks = 0; ks < 2; ++ks)
#pragma unroll
    for (int dt = 0; dt < 2; ++dt) {
      int j = ks * 2 + hi;
      Voff[ks][dt] = (256 + dt * 128 + ks * 64 + hi * 32 + (c ^ j)) * 8;
    }

  const __bf16* qbase = q + (rowBase + c) * 256 + wave * 64 + hi * 8;
  v8bf Qf[4];
#pragma unroll
  for (int kk = 0; kk < 4; ++kk) Qf[kk] = *(const v8bf*)(qbase + kk * 16);

  f32x16 O0 = {}, O1 = {};
  const f32x16 Z16 = {};
  float ls0 = 0.f, ls1 = 0.f, ls2 = 0.f, ls3 = 0.f;

  // prologue: tiles 0 -> buf0, 1 -> buf1 (4 loads in flight)
  GLOAD16(kg, kl);
  GLOAD16(vg, vl);
  GLOAD16(kg + 2048, kl + 4096);
  GLOAD16(vg + 32, vl + 4096);

  int cur = 0;  // buffer index of tile it; nxt2 = buffer of tile it+2
  int nxt2 = 2;
  for (int it = 0; it < 32; ++it) {
    // stage tile it+2, then ensure OWN stage(it) landed; barrier makes the
    // tile globally visible without draining the it+1/it+2 loads.
    if (it < 30) {
      GLOAD16(kg + (it + 2) * 2048, kl + nxt2 * 4096);
      GLOAD16(vg + (it + 2) * 32, vl + nxt2 * 4096);
      asm volatile("s_waitcnt vmcnt(4)" ::: "memory");
    } else if (it == 30) {
      asm volatile("s_waitcnt vmcnt(2)" ::: "memory");
    } else {
      asm volatile("s_waitcnt vmcnt(0)" ::: "memory");
    }
    __builtin_amdgcn_sched_barrier(0);
    __builtin_amdgcn_s_barrier();
    __builtin_amdgcn_sched_barrier(0);

    const __bf16* base = &SMEM[cur * 4096];
    v8bf Kf[4], Vf[2][2];
#pragma unroll
    for (int kk = 0; kk < 4; ++kk) Kf[kk] = *(const v8bf*)(base + Koff[kk]);
#pragma unroll
    for (int ks = 0; ks < 2; ++ks)
#pragma unroll
      for (int dt = 0; dt < 2; ++dt)
        Vf[ks][dt] = *(const v8bf*)(base + Voff[ks][dt]);

    f32x16 S = MFMA32(Kf[0], Qf[0], Z16);
    S = MFMA32(Kf[1], Qf[1], S);
    S = MFMA32(Kf[2], Qf[2], S);
    S = MFMA32(Kf[3], Qf[3], S);

    // exp2-direct (Q pre-scaled by log2(e)); fp32 tree partial sums
#pragma unroll
    for (int r = 0; r < 16; ++r) S[r] = __builtin_amdgcn_exp2f(S[r]);
    ls0 += (S[0] + S[1]) + (S[2] + S[3]);
    ls1 += (S[4] + S[5]) + (S[6] + S[7]);
    ls2 += (S[8] + S[9]) + (S[10] + S[11]);
    ls3 += (S[12] + S[13]) + (S[14] + S[15]);

    int w[8];
#pragma unroll
    for (int q2 = 0; q2 < 8; ++q2) {
      int r;
      asm("v_cvt_pk_bf16_f32 %0, %1, %2"
          : "=v"(r) : "v"(S[2 * q2]), "v"(S[2 * q2 + 1]));
      w[q2] = r;
    }
    v2i s1 = __builtin_amdgcn_permlane32_swap(w[2], w[0], false, false);
    v2i s2 = __builtin_amdgcn_permlane32_swap(w[3], w[1], false, false);
    v2i s3 = __builtin_amdgcn_permlane32_swap(w[6], w[4], false, false);
    v2i s4 = __builtin_amdgcn_permlane32_swap(w[7], w[5], false, false);
    v4i pa0i, pa1i;
    pa0i[0] = s1[1]; pa0i[1] = s2[1]; pa0i[2] = s1[0]; pa0i[3] = s2[0];
    pa1i[0] = s3[1]; pa1i[1] = s4[1]; pa1i[2] = s3[0]; pa1i[3] = s4[0];
    v8bf pa0 = *(v8bf*)&pa0i, pa1 = *(v8bf*)&pa1i;

    O0 = MFMA32(pa0, Vf[0][0], O0);
    O1 = MFMA32(pa0, Vf[0][1], O1);
    O0 = MFMA32(pa1, Vf[1][0], O0);
    O1 = MFMA32(pa1, Vf[1][1], O1);

    cur = (cur == 2) ? 0 : cur + 1;
    nxt2 = (nxt2 == 2) ? 0 : nxt2 + 1;
  }

  float lsum = (ls0 + ls1) + (ls2 + ls3);
  float tot = lsum + __shfl_xor(lsum, 32);
  float linv = 1.0f / tot;  // lane c holds 1/l for q-row c

  __syncthreads();  // all waves done reading KV -> union region free

  // normalized O (bf16, same rounding as the old pv store) -> LDS
  __bf16(*Ot)[264] = (__bf16(*)[264])SMEM;
#pragma unroll
  for (int r = 0; r < 16; ++r) {
    int qr = (r & 3) + 8 * (r >> 2) + 4 * hi;
    float li = __shfl(linv, qr);
    Ot[qr][wave * 64 + c] = (__bf16)(O0[r] * li);
    Ot[qr][wave * 64 + 32 + c] = (__bf16)(O1[r] * li);
  }
  __syncthreads();

  // out-projection: wave handles out-cols n0 = wave*64 (old k_out inner loop)
  int g = lane >> 4, c16 = lane & 15;
  const v8bf* wf = (const v8bf*)owfrag;
  f32x4 acc[2][4];
#pragma unroll
  for (int m = 0; m < 2; ++m)
#pragma unroll
    for (int n = 0; n < 4; ++n) acc[m][n] = f32x4{0.f, 0.f, 0.f, 0.f};
#pragma unroll
  for (int kk = 0; kk < 8; ++kk) {
    v8bf a0 = *(const v8bf*)&Ot[c16][kk * 32 + 8 * g];
    v8bf a1 = *(const v8bf*)&Ot[16 + c16][kk * 32 + 8 * g];
    v8bf bf[4];
#pragma unroll
    for (int n = 0; n < 4; ++n)
      bf[n] = wf[(((wave * 8 + kk) * 4 + n) << 6) | lane];
#pragma unroll
    for (int n = 0; n < 4; ++n) {
      acc[0][n] = MFMA16(a0, bf[n], acc[0][n]);
      acc[1][n] = MFMA16(a1, bf[n], acc[1][n]);
    }
  }
#pragma unroll
  for (int n = 0; n < 4; ++n) {
    int col = wave * 64 + n * 16 + c16;
    float bias = ob[col];
#pragma unroll
    for (int m = 0; m < 2; ++m)
#pragma unroll
      for (int j = 0; j < 4; ++j) {
        int row = m * 16 + 4 * g + j;
        out[(rowBase + row) * 256 + col] = acc[m][n][j] + bias;
      }
  }
}

// ---------------- launcher ----------------
extern "C" void kernel_launch(void* const* d_in, const int* in_sizes, int n_in,
                              void* d_out, int out_size, void* d_ws, size_t ws_size,
                              hipStream_t stream) {
  const float* x   = (const float*)d_in[0];
  const float* qw  = (const float*)d_in[1];
  const float* qb  = (const float*)d_in[2];
  const float* kw  = (const float*)d_in[3];
  const float* kb  = (const float*)d_in[4];
  const float* vw  = (const float*)d_in[5];
  const float* vb  = (const float*)d_in[6];
  const float* kcw = (const float*)d_in[7];
  const float* kcb = (const float*)d_in[8];
  const float* vcw = (const float*)d_in[9];
  const float* vcb = (const float*)d_in[10];
  const float* ow  = (const float*)d_in[11];
  const float* ob  = (const float*)d_in[12];
  float* out = (float*)d_out;
  char* ws = (char*)d_ws;

  __bf16* qbuf   = (__bf16*)(ws + 16777216);   // 16,777,216
  __bf16* klin   = (__bf16*)(ws + 33554432);   //  4,194,304
  __bf16* vlin   = (__bf16*)(ws + 37748736);   //  4,194,304
  __bf16* kc     = (__bf16*)(ws + 41943040);   //  1,048,576
  __bf16* vcT    = (__bf16*)(ws + 42991616);   //  1,048,576
  __bf16* wfrag  = (__bf16*)(ws + 44040192);   //    196,608
  __bf16* owfrag = (__bf16*)(ws + 44236800);   //    131,072

  k_cvt_w<<<640, 256, 0, stream>>>(qw, kw, vw, ow, wfrag, owfrag);
  k_qkv<<<512, 256, 0, stream>>>(x, wfrag, qb, kb, vb, qbuf, klin, vlin);
  k_conv<<<256, 256, 0, stream>>>(klin, vlin, kcw, kcb, vcw, vcb, kc, vcT);
  k_attn<<<1024, 256, 0, stream>>>(qbuf, kc, vcT, owfrag, ob, out);
}

// Round 14
// 95.558 us; speedup vs baseline: 1.1365x; 1.0117x over previous
//
#include <hip/hip_runtime.h>
#include <hip/hip_bf16.h>

typedef __bf16 v8bf __attribute__((ext_vector_type(8)));
typedef float f32x4 __attribute__((ext_vector_type(4)));
typedef float f32x16 __attribute__((ext_vector_type(16)));
typedef int v2i __attribute__((ext_vector_type(2)));
typedef int v4i __attribute__((ext_vector_type(4)));

#define MFMA16(a, b, c) __builtin_amdgcn_mfma_f32_16x16x32_bf16(a, b, c, 0, 0, 0)
#define MFMA32(a, b, c) __builtin_amdgcn_mfma_f32_32x32x16_bf16(a, b, c, 0, 0, 0)
#define GLOAD16(gp, lp)                                                        \
  __builtin_amdgcn_global_load_lds(                                            \
      (const __attribute__((address_space(1))) void*)(gp),                     \
      (__attribute__((address_space(3))) void*)(lp), 16, 0, 0)

// q scale = SCALE * log2(e) so that exp2(qk) == exp(qk*SCALE)
#define QSCALE 0.18033688011112042f

// ---------------- K0: weights -> MFMA-fragment-ordered bf16 ----------------
__global__ __launch_bounds__(256) void k_cvt_w(const float* __restrict__ qw,
                                               const float* __restrict__ kw,
                                               const float* __restrict__ vw,
                                               const float* __restrict__ ow,
                                               __bf16* __restrict__ wfrag,
                                               __bf16* __restrict__ owfrag) {
  int t = blockIdx.x * 256 + threadIdx.x;  // 640*256 = 163840
  if (t < 98304) {
    int e = t & 7, idx = t >> 3;
    int l = idx & 63; idx >>= 6;
    int n = idx & 3; idx >>= 2;
    int kk = idx & 7, nb = idx >> 3;
    int nn = nb * 64 + n * 16 + (l & 15);
    int k = kk * 32 + 8 * (l >> 4) + e;
    float v;
    if (nn < 256) v = qw[k * 256 + nn] * QSCALE;
    else if (nn < 320) v = kw[k * 64 + (nn - 256)];
    else v = vw[k * 64 + (nn - 320)];
    wfrag[t] = (__bf16)v;
  } else {
    int u = t - 98304;
    int e = u & 7, idx = u >> 3;
    int l = idx & 63; idx >>= 6;
    int n = idx & 3; idx >>= 2;
    int kk = idx & 7, nb = idx >> 3;
    int nn = nb * 64 + n * 16 + (l & 15);
    int k = kk * 32 + 8 * (l >> 4) + e;
    owfrag[u] = (__bf16)ow[k * 256 + nn];
  }
}

// ---------------- K1: fused QKV projection GEMM, x read ONCE --------------
__global__ __launch_bounds__(256) void k_qkv(const float* __restrict__ x,
                                             const __bf16* __restrict__ wfrag,
                                             const float* __restrict__ qb,
                                             const float* __restrict__ kb,
                                             const float* __restrict__ vb,
                                             __bf16* __restrict__ qo,
                                             __bf16* __restrict__ klin,
                                             __bf16* __restrict__ vlin) {
  int bx = blockIdx.x;
  int mb = (bx & 7) * 64 + (bx >> 3);  // 512 % 8 == 0: bijective XCD chunk
  int wave = threadIdx.x >> 6, lane = threadIdx.x & 63;
  int g = lane >> 4, c = lane & 15;
  int r0 = mb * 64 + wave * 16;
  const v8bf* wf = (const v8bf*)wfrag;

  v8bf a[8];
#pragma unroll
  for (int kk = 0; kk < 8; ++kk) {
    const float* ap = x + (size_t)(r0 + c) * 256 + kk * 32 + 8 * g;
    float4 f0 = *(const float4*)ap;
    float4 f1 = *(const float4*)(ap + 4);
    v8bf t;
    t[0] = (__bf16)f0.x; t[1] = (__bf16)f0.y; t[2] = (__bf16)f0.z; t[3] = (__bf16)f0.w;
    t[4] = (__bf16)f1.x; t[5] = (__bf16)f1.y; t[6] = (__bf16)f1.z; t[7] = (__bf16)f1.w;
    a[kk] = t;
  }
#pragma unroll
  for (int nb = 0; nb < 6; ++nb) {
    int n0 = nb * 64;
    f32x4 acc[4];
#pragma unroll
    for (int n = 0; n < 4; ++n) acc[n] = f32x4{0.f, 0.f, 0.f, 0.f};
#pragma unroll
    for (int kk = 0; kk < 8; ++kk) {
      v8bf bf[4];
#pragma unroll
      for (int n = 0; n < 4; ++n)
        bf[n] = wf[(((nb * 8 + kk) * 4 + n) << 6) | lane];
#pragma unroll
      for (int n = 0; n < 4; ++n) acc[n] = MFMA16(a[kk], bf[n], acc[n]);
    }
#pragma unroll
    for (int n = 0; n < 4; ++n) {
      int col = n0 + n * 16 + c;
      float bias;
      if (col < 256) bias = qb[col] * QSCALE;
      else if (col < 320) bias = kb[col - 256];
      else bias = vb[col - 320];
#pragma unroll
      for (int j = 0; j < 4; ++j) {
        int row = r0 + 4 * g + j;
        float v = acc[n][j] + bias;
        if (col < 256) qo[(size_t)row * 256 + col] = (__bf16)v;
        else if (col < 320) klin[(size_t)row * 64 + (col - 256)] = (__bf16)v;
        else vlin[(size_t)row * 64 + (col - 320)] = (__bf16)v;
      }
    }
  }
}

// ---------------- K2: depthwise 3x3 stride-2 conv (R11 original) ----------
__global__ __launch_bounds__(256) void k_conv(const __bf16* __restrict__ klin,
                                              const __bf16* __restrict__ vlin,
                                              const float* __restrict__ kw,
                                              const float* __restrict__ kbias,
                                              const float* __restrict__ vw,
                                              const float* __restrict__ vbias,
                                              __bf16* __restrict__ kc,
                                              __bf16* __restrict__ vcT) {
  __shared__ __bf16 VT[32][66];
  int bx = blockIdx.x;
  int b = bx >> 5, pt = bx & 31;
  int t = threadIdx.x;
  int ch = t & 63, pg = t >> 6;
  float kwv[9], vwv[9];
#pragma unroll
  for (int i = 0; i < 9; ++i) { kwv[i] = kw[i * 64 + ch]; vwv[i] = vw[i * 64 + ch]; }
  float kb0 = kbias[ch], vb0 = vbias[ch];
  const __bf16* kin = klin + (size_t)b * 262144;
  const __bf16* vin = vlin + (size_t)b * 262144;
#pragma unroll
  for (int i = 0; i < 8; ++i) {
    int pl = pg * 8 + i;
    int p = pt * 32 + pl;
    int oy = p >> 5, ox = p & 31;
    float ak = kb0, av = vb0;
#pragma unroll
    for (int dy = 0; dy < 3; ++dy) {
      int iy = 2 * oy - 1 + dy;
      if (iy < 0 || iy > 63) continue;
#pragma unroll
      for (int dx = 0; dx < 3; ++dx) {
        int ix = 2 * ox - 1 + dx;
        if (ix < 0 || ix > 63) continue;
        size_t src = ((size_t)iy * 64 + ix) * 64 + ch;
        ak += (float)kin[src] * kwv[dy * 3 + dx];
        av += (float)vin[src] * vwv[dy * 3 + dx];
      }
    }
    kc[((size_t)b * 1024 + p) * 64 + ch] = (__bf16)ak;
    VT[pl][ch] = (__bf16)av;
  }
  __syncthreads();
  int row = t >> 2, c0 = (t & 3) * 8;
  __bf16 tmp[8];
#pragma unroll
  for (int i = 0; i < 8; ++i) tmp[i] = VT[c0 + i][row];
  *(v4i*)(vcT + (size_t)b * 65536 + row * 1024 + pt * 32 + c0) = *(v4i*)tmp;
}

// ---------------- K2b: repack kc/vcT -> staging-linear kcS/vcS ------------
// Reads the EXACT addresses R11's attn GLOAD16s read for (tile, chunk u),
// writes them contiguous. Pure data movement -> attn LDS bytes identical.
__global__ __launch_bounds__(256) void k_repack(const __bf16* __restrict__ kc,
                                                const __bf16* __restrict__ vcT,
                                                __bf16* __restrict__ kcS,
                                                __bf16* __restrict__ vcS) {
  int b = blockIdx.x >> 5, tile = blockIdx.x & 31;
  int u = threadIdx.x;
  int kj = u >> 5, kr = (u & 31) ^ kj;
  v4i kv = *(const v4i*)(kc + (size_t)b * 65536 + (size_t)tile * 2048 +
                         kr * 64 + kj * 8);
  *(v4i*)(kcS + ((size_t)b * 32 + tile) * 2048 + u * 8) = kv;
  int dt = u >> 7, ks = (u >> 6) & 1, vh = (u >> 5) & 1;
  int cc = (u & 31) ^ (ks * 2 + vh);
  v4i vv = *(const v4i*)(vcT + (size_t)b * 65536 + (size_t)(dt * 32 + cc) * 1024 +
                         tile * 32 + ks * 16 + vh * 8);
  *(v4i*)(vcS + ((size_t)b * 32 + tile) * 2048 + u * 8) = vv;
}

// ---------------- K3: MQA flash attention + fused out-projection ----------
// grid 1024 = 8 b x 128 qtiles; 4 waves = 4 heads of the same 32 q rows.
// RACE-FIXED counted-vmcnt 3-buffer pipeline: per iter
//   {vmcnt(2) -> barrier -> GLOAD tile it+2 -> reads/compute}.
// The GLOAD into buf[(it+2)%3] (== buf[(it-1)%3]) now issues only AFTER the
// barrier that proves all waves finished reading tile it-1 from it. vmcnt(2)
// before the barrier guarantees tile it has landed (only tile it+1's 2 loads
// may remain outstanding).
__global__ __launch_bounds__(256) void k_attn(const __bf16* __restrict__ q,
                                              const __bf16* __restrict__ kcS,
                                              const __bf16* __restrict__ vcS,
                                              const __bf16* __restrict__ owfrag,
                                              const float* __restrict__ ob,
                                              float* __restrict__ out) {
  __shared__ __bf16 SMEM[12288];  // 3 bufs x (K 2048 + V 2048) / Ot[32][264]
  int bx = blockIdx.x;
  int L = (bx & 7) * 128 + (bx >> 3);
  int b = L >> 7, qt = L & 127;
  int wave = threadIdx.x >> 6, lane = threadIdx.x & 63;  // wave == head
  int c = lane & 31, hi = lane >> 5;
  int t = threadIdx.x;
  size_t rowBase = (size_t)b * 4096 + qt * 32;

  // staging sources: contiguous per tile (2048 elems each for K and V)
  const __bf16* kg = kcS + (size_t)b * 65536 + t * 8;
  const __bf16* vg = vcS + (size_t)b * 65536 + t * 8;
  __bf16* kl = &SMEM[t * 8];
  __bf16* vl = &SMEM[2048 + t * 8];

  int Koff[4], Voff[2][2];
#pragma unroll
  for (int kk = 0; kk < 4; ++kk) {
    int j = kk * 2 + hi;
    Koff[kk] = (j * 32 + (c ^ j)) * 8;
  }
#pragma unroll
  for (int ks = 0; ks < 2; ++ks)
#pragma unroll
    for (int dt = 0; dt < 2; ++dt) {
      int j = ks * 2 + hi;
      Voff[ks][dt] = (256 + dt * 128 + ks * 64 + hi * 32 + (c ^ j)) * 8;
    }

  const __bf16* qbase = q + (rowBase + c) * 256 + wave * 64 + hi * 8;
  v8bf Qf[4];
#pragma unroll
  for (int kk = 0; kk < 4; ++kk) Qf[kk] = *(const v8bf*)(qbase + kk * 16);

  f32x16 O0 = {}, O1 = {};
  const f32x16 Z16 = {};
  float ls0 = 0.f, ls1 = 0.f, ls2 = 0.f, ls3 = 0.f;

  // prologue: tiles 0 -> buf0, 1 -> buf1 (4 loads in flight)
  GLOAD16(kg, kl);
  GLOAD16(vg, vl);
  GLOAD16(kg + 2048, kl + 4096);
  GLOAD16(vg + 2048, vl + 4096);

  int cur = 0;  // buffer index of tile it; nxt2 = buffer of tile it+2
  int nxt2 = 2;
  for (int it = 0; it < 32; ++it) {
    // own tile-it loads landed (only tile it+1's 2 loads may be in flight)
    if (it < 31) {
      asm volatile("s_waitcnt vmcnt(2)" ::: "memory");
    } else {
      asm volatile("s_waitcnt vmcnt(0)" ::: "memory");
    }
    __builtin_amdgcn_sched_barrier(0);
    __builtin_amdgcn_s_barrier();
    __builtin_amdgcn_sched_barrier(0);
    // barrier crossed: all waves done with tile it-1's buffer -> safe to
    // overwrite it with tile it+2.
    if (it < 30) {
      GLOAD16(kg + (it + 2) * 2048, kl + nxt2 * 4096);
      GLOAD16(vg + (it + 2) * 2048, vl + nxt2 * 4096);
    }

    const __bf16* base = &SMEM[cur * 4096];
    v8bf Kf[4], Vf[2][2];
#pragma unroll
    for (int kk = 0; kk < 4; ++kk) Kf[kk] = *(const v8bf*)(base + Koff[kk]);
#pragma unroll
    for (int ks = 0; ks < 2; ++ks)
#pragma unroll
      for (int dt = 0; dt < 2; ++dt)
        Vf[ks][dt] = *(const v8bf*)(base + Voff[ks][dt]);

    f32x16 S = MFMA32(Kf[0], Qf[0], Z16);
    S = MFMA32(Kf[1], Qf[1], S);
    S = MFMA32(Kf[2], Qf[2], S);
    S = MFMA32(Kf[3], Qf[3], S);

    // exp2-direct (Q pre-scaled by log2(e)); fp32 tree partial sums
#pragma unroll
    for (int r = 0; r < 16; ++r) S[r] = __builtin_amdgcn_exp2f(S[r]);
    ls0 += (S[0] + S[1]) + (S[2] + S[3]);
    ls1 += (S[4] + S[5]) + (S[6] + S[7]);
    ls2 += (S[8] + S[9]) + (S[10] + S[11]);
    ls3 += (S[12] + S[13]) + (S[14] + S[15]);

    int w[8];
#pragma unroll
    for (int q2 = 0; q2 < 8; ++q2) {
      int r;
      asm("v_cvt_pk_bf16_f32 %0, %1, %2"
          : "=v"(r) : "v"(S[2 * q2]), "v"(S[2 * q2 + 1]));
      w[q2] = r;
    }
    v2i s1 = __builtin_amdgcn_permlane32_swap(w[2], w[0], false, false);
    v2i s2 = __builtin_amdgcn_permlane32_swap(w[3], w[1], false, false);
    v2i s3 = __builtin_amdgcn_permlane32_swap(w[6], w[4], false, false);
    v2i s4 = __builtin_amdgcn_permlane32_swap(w[7], w[5], false, false);
    v4i pa0i, pa1i;
    pa0i[0] = s1[1]; pa0i[1] = s2[1]; pa0i[2] = s1[0]; pa0i[3] = s2[0];
    pa1i[0] = s3[1]; pa1i[1] = s4[1]; pa1i[2] = s3[0]; pa1i[3] = s4[0];
    v8bf pa0 = *(v8bf*)&pa0i, pa1 = *(v8bf*)&pa1i;

    O0 = MFMA32(pa0, Vf[0][0], O0);
    O1 = MFMA32(pa0, Vf[0][1], O1);
    O0 = MFMA32(pa1, Vf[1][0], O0);
    O1 = MFMA32(pa1, Vf[1][1], O1);

    cur = (cur == 2) ? 0 : cur + 1;
    nxt2 = (nxt2 == 2) ? 0 : nxt2 + 1;
  }

  float lsum = (ls0 + ls1) + (ls2 + ls3);
  float tot = lsum + __shfl_xor(lsum, 32);
  float linv = 1.0f / tot;  // lane c holds 1/l for q-row c

  __syncthreads();  // all waves done reading KV -> union region free

  // normalized O (bf16, same rounding as the old pv store) -> LDS
  __bf16(*Ot)[264] = (__bf16(*)[264])SMEM;
#pragma unroll
  for (int r = 0; r < 16; ++r) {
    int qr = (r & 3) + 8 * (r >> 2) + 4 * hi;
    float li = __shfl(linv, qr);
    Ot[qr][wave * 64 + c] = (__bf16)(O0[r] * li);
    Ot[qr][wave * 64 + 32 + c] = (__bf16)(O1[r] * li);
  }
  __syncthreads();

  // out-projection: wave handles out-cols n0 = wave*64 (old k_out inner loop)
  int g = lane >> 4, c16 = lane & 15;
  const v8bf* wf = (const v8bf*)owfrag;
  f32x4 acc[2][4];
#pragma unroll
  for (int m = 0; m < 2; ++m)
#pragma unroll
    for (int n = 0; n < 4; ++n) acc[m][n] = f32x4{0.f, 0.f, 0.f, 0.f};
#pragma unroll
  for (int kk = 0; kk < 8; ++kk) {
    v8bf a0 = *(const v8bf*)&Ot[c16][kk * 32 + 8 * g];
    v8bf a1 = *(const v8bf*)&Ot[16 + c16][kk * 32 + 8 * g];
    v8bf bf[4];
#pragma unroll
    for (int n = 0; n < 4; ++n)
      bf[n] = wf[(((wave * 8 + kk) * 4 + n) << 6) | lane];
#pragma unroll
    for (int n = 0; n < 4; ++n) {
      acc[0][n] = MFMA16(a0, bf[n], acc[0][n]);
      acc[1][n] = MFMA16(a1, bf[n], acc[1][n]);
    }
  }
#pragma unroll
  for (int n = 0; n < 4; ++n) {
    int col = wave * 64 + n * 16 + c16;
    float bias = ob[col];
#pragma unroll
    for (int m = 0; m < 2; ++m)
#pragma unroll
      for (int j = 0; j < 4; ++j) {
        int row = m * 16 + 4 * g + j;
        out[(rowBase + row) * 256 + col] = acc[m][n][j] + bias;
      }
  }
}

// ---------------- launcher ----------------
extern "C" void kernel_launch(void* const* d_in, const int* in_sizes, int n_in,
                              void* d_out, int out_size, void* d_ws, size_t ws_size,
                              hipStream_t stream) {
  const float* x   = (const float*)d_in[0];
  const float* qw  = (const float*)d_in[1];
  const float* qb  = (const float*)d_in[2];
  const float* kw  = (const float*)d_in[3];
  const float* kb  = (const float*)d_in[4];
  const float* vw  = (const float*)d_in[5];
  const float* vb  = (const float*)d_in[6];
  const float* kcw = (const float*)d_in[7];
  const float* kcb = (const float*)d_in[8];
  const float* vcw = (const float*)d_in[9];
  const float* vcb = (const float*)d_in[10];
  const float* ow  = (const float*)d_in[11];
  const float* ob  = (const float*)d_in[12];
  float* out = (float*)d_out;
  char* ws = (char*)d_ws;

  __bf16* kcS    = (__bf16*)(ws + 0);          //  1,048,576 (staging-linear)
  __bf16* vcS    = (__bf16*)(ws + 1048576);    //  1,048,576 (staging-linear)
  __bf16* qbuf   = (__bf16*)(ws + 16777216);   // 16,777,216
  __bf16* klin   = (__bf16*)(ws + 33554432);   //  4,194,304
  __bf16* vlin   = (__bf16*)(ws + 37748736);   //  4,194,304
  __bf16* kc     = (__bf16*)(ws + 41943040);   //  1,048,576
  __bf16* vcT    = (__bf16*)(ws + 42991616);   //  1,048,576
  __bf16* wfrag  = (__bf16*)(ws + 44040192);   //    196,608
  __bf16* owfrag = (__bf16*)(ws + 44236800);   //    131,072

  k_cvt_w<<<640, 256, 0, stream>>>(qw, kw, vw, ow, wfrag, owfrag);
  k_qkv<<<512, 256, 0, stream>>>(x, wfrag, qb, kb, vb, qbuf, klin, vlin);
  k_conv<<<256, 256, 0, stream>>>(klin, vlin, kcw, kcb, vcw, vcb, kc, vcT);
  k_repack<<<256, 256, 0, stream>>>(kc, vcT, kcS, vcS);
  k_attn<<<1024, 256, 0, stream>>>(qbuf, kcS, vcS, owfrag, ob, out);
}